// Round 10
// baseline (258.634 us; speedup 1.0000x reference)
//
#include <hip/hip_runtime.h>

#define CH 128
#define DS 24
#define HW (DS*DS)      // 576
#define VS (DS*DS*DS)   // 13824

typedef _Float16 f16x8 __attribute__((ext_vector_type(8)));
typedef _Float16 half2v __attribute__((ext_vector_type(2)));
typedef __attribute__((ext_vector_type(4))) float f32x4;
typedef _Float16 h4 __attribute__((ext_vector_type(4)));

__device__ __forceinline__ half2v u2h(unsigned u) {
  union { unsigned u; half2v h; } v; v.u = u; return v.h;
}
__device__ __forceinline__ unsigned h2u(half2v h) {
  union { unsigned u; half2v h; } v; v.h = h; return v.u;
}

// sum of 3 fp16 offset partials + bias, row = 3*kn+a
__device__ __forceinline__ float off_sum(const _Float16* __restrict__ OFFp,
                                         const float* __restrict__ b_off,
                                         int kn, int a, int mv) {
  int row = 3*kn + a;
  return (float)OFFp[row*VS + mv] + (float)OFFp[(81 + row)*VS + mv]
       + (float)OFFp[(162 + row)*VS + mv] + b_off[row];
}

// one trilinear corner for tap kn -> *Mslot
__device__ __forceinline__ void meta1(int kn, int mz, int my, int mx,
                                      float po0, float po1, float po2,
                                      int corner, uint2* Mslot) {
  float cz = (float)(mz + kn/9     - 1) + po0;
  float cy = (float)(my + (kn/3)%3 - 1) + po1;
  float cx = (float)(mx + kn%3     - 1) + po2;
  float fz = floorf(cz), fy = floorf(cy), fx = floorf(cx);
  int iz = (int)fz, iy = (int)fy, ix = (int)fx;
  float rz = cz - fz, ry = cy - fy, rx = cx - fx;
  int ca = corner >> 2, cb = (corner >> 1) & 1, cc = corner & 1;
  int zi = iz + ca, yi = iy + cb, xi = ix + cc;
  float ww = (ca ? rz : 1.f-rz) * (cb ? ry : 1.f-ry) * (cc ? rx : 1.f-rx);
  bool valid = ((unsigned)zi < 24u) && ((unsigned)yi < 24u) && ((unsigned)xi < 24u);
  float wv = valid ? ww : 0.f;
  half2v wp = {(_Float16)wv, (_Float16)wv};
  int idx = valid ? (zi*DS + yi)*DS + xi : 0;
  *Mslot = make_uint2(h2u(wp), (unsigned)(idx << 7));
}

// gather one tap's 32x128 B-tile into BlBuf using meta Mb
__device__ __forceinline__ void gather_tap32(
    const _Float16* __restrict__ A2th, const uint2 (*Mb)[8],
    _Float16* BlBuf, int cq, int vi0) {
  #pragma unroll
  for (int p = 0; p < 2; ++p) {
    int vl = (p << 4) + vi0;
    half2v a0 = {(_Float16)0.f, (_Float16)0.f};
    half2v a1 = a0, a2 = a0, a3 = a0;
    #pragma unroll
    for (int corner = 0; corner < 8; ++corner) {
      uint2 m = Mb[vl][corner];
      half2v wp = u2h(m.x);
      uint4 g = *(const uint4*)&A2th[m.y + (cq << 3)];
      a0 += u2h(g.x) * wp;
      a1 += u2h(g.y) * wp;
      a2 += u2h(g.z) * wp;
      a3 += u2h(g.w) * wp;
    }
    uint4 pk = {h2u(a0), h2u(a1), h2u(a2), h2u(a3)};
    *(uint4*)&BlBuf[vl*128 + ((cq ^ (vl & 15)) << 3)] = pk;
  }
}

// offconv B chunk: masked shifted-row load / swizzled store
__device__ __forceinline__ uint4 ld_chunk(const _Float16* __restrict__ A2th,
                                          int vb, int s, int k) {
  int vl = s >> 4, cq = s & 15;
  int v = vb + vl;
  int z = v / HW, y = (v / DS) % DS, xx = v % DS;
  int dz = k/9 - 1, dy = (k/3)%3 - 1, dx = k%3 - 1;
  uint4 pk = {0u,0u,0u,0u};
  int zz = z + dz, yy = y + dy, xq = xx + dx;
  if ((unsigned)zz < 24u && (unsigned)yy < 24u && (unsigned)xq < 24u)
    pk = *(const uint4*)&A2th[(v + (dz*DS + dy)*DS + dx)*CH + (cq << 3)];
  return pk;
}
__device__ __forceinline__ void st_chunk(_Float16* Bb, int s, uint4 pk) {
  int vl = s >> 4, cq = s & 15;
  *(uint4*)&Bb[vl*128 + ((cq ^ (vl & 15)) << 3)] = pk;
}

// ---------------------------------------------------------------------------
// K0: weight prep, coalesced via LDS transpose.
// ---------------------------------------------------------------------------
__global__ __launch_bounds__(256) void prep_weights(
    const float* __restrict__ w_off, const float* __restrict__ w_def,
    const float* __restrict__ w1,
    _Float16* __restrict__ WTh, _Float16* __restrict__ WDh,
    _Float16* __restrict__ W1h) {
  __shared__ float sbuf[3456];
  const int b = blockIdx.x, t = threadIdx.x;
  if (b < 96) {
    const int o = b;
    if (o < 81) {
      for (int s = t; s < 3456; s += 256) sbuf[s] = w_off[o*3456 + s];
      __syncthreads();
      for (int s = t; s < 3456; s += 256) {
        int k = s >> 7, c = s & 127;
        WTh[(k*96 + o)*128 + c] = (_Float16)sbuf[c*27 + k];
      }
    } else {
      for (int s = t; s < 3456; s += 256) {
        int k = s >> 7, c = s & 127;
        WTh[(k*96 + o)*128 + c] = (_Float16)0.f;
      }
    }
  } else if (b < 224) {
    const int o = b - 96;
    for (int s = t; s < 3456; s += 256) sbuf[s] = w_def[o*3456 + s];
    __syncthreads();
    for (int s = t; s < 3456; s += 256) {
      int k = s >> 7, c = s & 127;
      WDh[(k*128 + o)*128 + c] = (_Float16)sbuf[c*27 + k];
    }
  } else {
    for (int s = t; s < 16384; s += 256) W1h[s] = (_Float16)w1[s];
  }
}

// ---------------------------------------------------------------------------
// K1: depthwise 5x5x5, pad=2 — LDS-free row-register version.
// ---------------------------------------------------------------------------
__global__ __launch_bounds__(192) void dw5_kernel(
    const float* __restrict__ x, const float* __restrict__ w0,
    const float* __restrict__ b0, float* __restrict__ A1) {
  const int c  = blockIdx.x / 3;
  const int zb = (blockIdx.x % 3) * 8;
  __shared__ float sw[125];
  const int t = threadIdx.x;
  if (t < 125) sw[t] = w0[c*125 + t];
  __syncthreads();
  const int z = zb + t / 24, y = t % 24;
  const float* xc = x + c*VS;
  float acc[24];
  #pragma unroll
  for (int o = 0; o < 24; ++o) acc[o] = 0.f;
  #pragma unroll
  for (int kz = 0; kz < 5; ++kz) {
    int zz = z + kz - 2;
    if ((unsigned)zz >= 24u) continue;
    #pragma unroll
    for (int ky = 0; ky < 5; ++ky) {
      int yy = y + ky - 2;
      if ((unsigned)yy >= 24u) continue;
      const float* row = &xc[(zz*DS + yy)*DS];
      float f[24];
      #pragma unroll
      for (int q = 0; q < 6; ++q) {
        float4 r = *(const float4*)(row + 4*q);
        f[4*q] = r.x; f[4*q+1] = r.y; f[4*q+2] = r.z; f[4*q+3] = r.w;
      }
      const float* wr = &sw[(kz*5 + ky)*5];
      #pragma unroll
      for (int kx = 0; kx < 5; ++kx) {
        float w = wr[kx];
        #pragma unroll
        for (int o = 0; o < 24; ++o) {
          int xi = o + kx - 2;
          if (xi >= 0 && xi < 24) acc[o] = fmaf(w, f[xi], acc[o]);
        }
      }
    }
  }
  const float bias = b0[c];
  float* orow = &A1[c*VS + (z*DS + y)*DS];
  #pragma unroll
  for (int q = 0; q < 6; ++q)
    *(float4*)(orow + 4*q) = make_float4(acc[4*q]+bias, acc[4*q+1]+bias,
                                         acc[4*q+2]+bias, acc[4*q+3]+bias);
}

// ---------------------------------------------------------------------------
// K2: depthwise 5x5x5 dil=3 pad=6 — LDS-free + fused fp16 transpose store.
// ---------------------------------------------------------------------------
__global__ __launch_bounds__(192) void dwdil_kernel(
    const float* __restrict__ A1, const float* __restrict__ wgt,
    const float* __restrict__ bs, _Float16* __restrict__ A2th) {
  const int c  = blockIdx.x / 3;
  const int zb = (blockIdx.x % 3) * 8;
  __shared__ float sw[125];
  const int t = threadIdx.x;
  if (t < 125) sw[t] = wgt[c*125 + t];
  __syncthreads();
  const int z = zb + t / 24, y = t % 24;
  const float* xc = A1 + c*VS;
  float acc[24];
  #pragma unroll
  for (int o = 0; o < 24; ++o) acc[o] = 0.f;
  #pragma unroll
  for (int kz = 0; kz < 5; ++kz) {
    int zz = z + 3*kz - 6;
    if ((unsigned)zz >= 24u) continue;
    #pragma unroll
    for (int ky = 0; ky < 5; ++ky) {
      int yy = y + 3*ky - 6;
      if ((unsigned)yy >= 24u) continue;
      const float* row = &xc[(zz*DS + yy)*DS];
      float f[24];
      #pragma unroll
      for (int q = 0; q < 6; ++q) {
        float4 r = *(const float4*)(row + 4*q);
        f[4*q] = r.x; f[4*q+1] = r.y; f[4*q+2] = r.z; f[4*q+3] = r.w;
      }
      const float* wr = &sw[(kz*5 + ky)*5];
      #pragma unroll
      for (int kx = 0; kx < 5; ++kx) {
        float w = wr[kx];
        #pragma unroll
        for (int o = 0; o < 24; ++o) {
          int xi = o + 3*kx - 6;
          if (xi >= 0 && xi < 24) acc[o] = fmaf(w, f[xi], acc[o]);
        }
      }
    }
  }
  const float bias = bs[c];
  _Float16* dst = &A2th[(z*DS + y)*DS*CH + c];
  #pragma unroll
  for (int o = 0; o < 24; ++o)
    dst[o*CH] = (_Float16)(acc[o] + bias);
}

// ---------------------------------------------------------------------------
// K4: offset conv, f16 MFMA, 32-v tiles -> grid 1296 (432 vt x 3 kg).
// 384 thr / 6 waves, wave = m-tile (A-frags direct from global).
// Double-buffered Bl (16 KB), single barrier per tap.
// ---------------------------------------------------------------------------
__global__ __launch_bounds__(384, 5) void offconv_kernel(
    const _Float16* __restrict__ A2th, const _Float16* __restrict__ WTh,
    _Float16* __restrict__ OFFp) {
  const int vb = (blockIdx.x % 432) * 32;
  const int kg = blockIdx.x / 432;          // 0..2
  __shared__ __align__(16) _Float16 Bl[2][32*128];  // 16 KB
  const int t    = threadIdx.x;
  const int lane = t & 63, w = t >> 6;      // w 0..5 = m-tile
  const int l16  = lane & 15, quad = lane >> 4;
  f32x4 acc[2];
  #pragma unroll
  for (int n = 0; n < 2; ++n) acc[n] = (f32x4){0.f,0.f,0.f,0.f};

  const int k0 = kg*9;
  {  // prologue: stage B(k0) -> Bl[0]  (512 chunks, 384 threads)
    uint4 c0 = ld_chunk(A2th, vb, t, k0);
    uint4 c1 = {0u,0u,0u,0u};
    if (t < 128) c1 = ld_chunk(A2th, vb, t + 384, k0);
    st_chunk(Bl[0], t, c0);
    if (t < 128) st_chunk(Bl[0], t + 384, c1);
  }
  __syncthreads();

  for (int i = 0; i < 9; ++i) {
    const int k = k0 + i, bi = i & 1;
    f16x8 af[4];
    #pragma unroll
    for (int ks = 0; ks < 4; ++ks)
      af[ks] = *(const f16x8*)&WTh[(k*96 + (w << 4) + l16)*128 + (ks << 5) + (quad << 3)];
    uint4 c0, c1;
    if (i < 8) {
      c0 = ld_chunk(A2th, vb, t, k + 1);
      if (t < 128) c1 = ld_chunk(A2th, vb, t + 384, k + 1);
    }
    #pragma unroll
    for (int ks = 0; ks < 4; ++ks) {
      int gx = (((ks << 2) + quad) ^ l16) << 3;
      #pragma unroll
      for (int n = 0; n < 2; ++n) {
        f16x8 bf = *(const f16x8*)&Bl[bi][((n << 4) + l16)*128 + gx];
        acc[n] = __builtin_amdgcn_mfma_f32_16x16x32_f16(af[ks], bf, acc[n], 0, 0, 0);
      }
    }
    if (i < 8) {
      st_chunk(Bl[bi ^ 1], t, c0);
      if (t < 128) st_chunk(Bl[bi ^ 1], t + 384, c1);
      __syncthreads();
    }
  }
  #pragma unroll
  for (int n = 0; n < 2; ++n)
    #pragma unroll
    for (int r = 0; r < 4; ++r) {
      int o = (w << 4) + (quad << 2) + r;
      if (o < 81)
        OFFp[(kg*81 + o)*VS + vb + (n << 4) + l16] = (_Float16)acc[n][r];
    }
}

// ---------------------------------------------------------------------------
// K5: deformable conv, f16 MFMA, 32-v tiles -> grid 1296 (432 vt x 3 kg).
// LDS 20 KB (Bl 2x8KB + M 2x2KB) -> ~7 blocks/CU co-resident.
// Single-barrier pipeline; meta = 1 corner/thread (32 vox x 8 = 256).
// ---------------------------------------------------------------------------
__global__ __launch_bounds__(256, 3) void deform_kernel(
    const _Float16* __restrict__ A2th, const _Float16* __restrict__ OFFp,
    const float* __restrict__ b_off, const _Float16* __restrict__ WDh,
    _Float16* __restrict__ D0, _Float16* __restrict__ D1,
    _Float16* __restrict__ D2) {
  const int vb = (blockIdx.x % 432) * 32;
  const int kg = blockIdx.x / 432;          // 0..2
  _Float16* DP = (kg == 0) ? D0 : (kg == 1) ? D1 : D2;
  __shared__ __align__(16) _Float16 Bl[2][32*128];  // 16 KB
  __shared__ uint2 M[2][32][8];                     // 4 KB
  const int t    = threadIdx.x;
  const int lane = t & 63, w = t >> 6;
  const int l16  = lane & 15, quad = lane >> 4;
  const int cq = t & 15, vi0 = t >> 4;      // gather: 16 voxel-slots x 16 cq
  const int mvl = t >> 3, mcr = t & 7;      // meta: voxel, corner
  const int mv = vb + mvl;
  const int mz = mv / HW, my = (mv / DS) % DS, mx = mv % DS;

  f32x4 acc[2][2];
  #pragma unroll
  for (int i = 0; i < 2; ++i)
    #pragma unroll
    for (int n = 0; n < 2; ++n) acc[i][n] = (f32x4){0.f,0.f,0.f,0.f};

  const int k0 = kg*9;
  {  // meta(k0) -> M[0]
    float p0 = off_sum(OFFp, b_off, k0, 0, mv);
    float p1 = off_sum(OFFp, b_off, k0, 1, mv);
    float p2 = off_sum(OFFp, b_off, k0, 2, mv);
    meta1(k0, mz, my, mx, p0, p1, p2, mcr, &M[0][mvl][mcr]);
  }
  __syncthreads();
  {  // gather(k0) -> Bl[0]; meta(k0+1) -> M[1]
    gather_tap32(A2th, M[0], Bl[0], cq, vi0);
    float p0 = off_sum(OFFp, b_off, k0+1, 0, mv);
    float p1 = off_sum(OFFp, b_off, k0+1, 1, mv);
    float p2 = off_sum(OFFp, b_off, k0+1, 2, mv);
    meta1(k0+1, mz, my, mx, p0, p1, p2, mcr, &M[1][mvl][mcr]);
  }
  __syncthreads();

  for (int i = 0; i < 9; ++i) {
    const int k = k0 + i, bi = i & 1;
    // A-fragments for tap k (issued first; gather waits cover them)
    f16x8 af0[4], af1[4];
    #pragma unroll
    for (int ks = 0; ks < 4; ++ks) {
      af0[ks] = *(const f16x8*)&WDh[(k*CH + (w<<5) + l16)*CH + (ks<<5) + (quad<<3)];
      af1[ks] = *(const f16x8*)&WDh[(k*CH + (w<<5) + 16 + l16)*CH + (ks<<5) + (quad<<3)];
    }
    if (i < 8) gather_tap32(A2th, M[bi ^ 1], Bl[bi ^ 1], cq, vi0);
    #pragma unroll
    for (int ks = 0; ks < 4; ++ks) {
      int gx = (((ks << 2) + quad) ^ l16) << 3;
      #pragma unroll
      for (int n = 0; n < 2; ++n) {
        f16x8 bf = *(const f16x8*)&Bl[bi][((n << 4) + l16)*128 + gx];
        acc[0][n] = __builtin_amdgcn_mfma_f32_16x16x32_f16(af0[ks], bf, acc[0][n], 0, 0, 0);
        acc[1][n] = __builtin_amdgcn_mfma_f32_16x16x32_f16(af1[ks], bf, acc[1][n], 0, 0, 0);
      }
    }
    if (i < 7) {
      float p0 = off_sum(OFFp, b_off, k+2, 0, mv);
      float p1 = off_sum(OFFp, b_off, k+2, 1, mv);
      float p2 = off_sum(OFFp, b_off, k+2, 2, mv);
      meta1(k+2, mz, my, mx, p0, p1, p2, mcr, &M[bi][mvl][mcr]);
    }
    if (i < 8) __syncthreads();
  }
  #pragma unroll
  for (int i = 0; i < 2; ++i)
    #pragma unroll
    for (int n = 0; n < 2; ++n)
      #pragma unroll
      for (int r = 0; r < 4; ++r) {
        int o = (w << 5) + (i << 4) + (quad << 2) + r;
        int v = vb + (n << 4) + l16;
        DP[o*VS + v] = (_Float16)acc[i][n][r];
      }
}

// ---------------------------------------------------------------------------
// K6: f16 MFMA 1x1x1 conv + x-multiply, 32-v tiles -> grid 432.
// ---------------------------------------------------------------------------
__global__ __launch_bounds__(256) void pw_mul_kernel(
    const _Float16* __restrict__ D0, const _Float16* __restrict__ D1,
    const _Float16* __restrict__ D2, const float* __restrict__ b_def,
    const _Float16* __restrict__ W1h, const float* __restrict__ b1,
    const float* __restrict__ x, float* __restrict__ out) {
  const int vb = blockIdx.x * 32;
  __shared__ __align__(16) _Float16 Wl[128*128]; // 32 KB
  __shared__ __align__(16) _Float16 Bl[32*128];  // 8 KB
  const int t    = threadIdx.x;
  const int lane = t & 63, w = t >> 6;
  const int l16  = lane & 15, quad = lane >> 4;
  const int wo = t >> 4, wcg = t & 15;
  #pragma unroll
  for (int i = 0; i < 8; ++i) {
    int o = wo + 16*i;
    *(uint4*)&Wl[o*128 + ((wcg ^ (o & 15)) << 3)] =
        *(const uint4*)&W1h[o*128 + (wcg << 3)];
  }
  {
    const int vsq = t & 7;     // v = 4*vsq..4*vsq+3
    const int c0  = t >> 3;    // c = c0 + 32*i
    #pragma unroll
    for (int i = 0; i < 4; ++i) {
      int c = c0 + (i << 5);
      float bd = b_def[c];
      int base = c*VS + vb + (vsq << 2);
      h4 a0 = *(const h4*)&D0[base];
      h4 a1 = *(const h4*)&D1[base];
      h4 a2 = *(const h4*)&D2[base];
      #pragma unroll
      for (int j = 0; j < 4; ++j) {
        float sum = (float)a0[j] + (float)a1[j] + (float)a2[j] + bd;
        int row = (vsq << 2) + j;
        Bl[row*128 + (((c >> 3) ^ (row & 15)) << 3) + (c & 7)] = (_Float16)sum;
      }
    }
  }
  __syncthreads();
  f32x4 acc[2][2];
  #pragma unroll
  for (int i = 0; i < 2; ++i)
    #pragma unroll
    for (int n = 0; n < 2; ++n) acc[i][n] = (f32x4){0.f,0.f,0.f,0.f};
  #pragma unroll
  for (int ks = 0; ks < 4; ++ks) {
    int gx = (((ks << 2) + quad) ^ l16) << 3;
    f16x8 a0 = *(const f16x8*)&Wl[((w << 5) + l16)*128 + gx];
    f16x8 a1 = *(const f16x8*)&Wl[((w << 5) + 16 + l16)*128 + gx];
    #pragma unroll
    for (int n = 0; n < 2; ++n) {
      f16x8 bf = *(const f16x8*)&Bl[((n << 4) + l16)*128 + gx];
      acc[0][n] = __builtin_amdgcn_mfma_f32_16x16x32_f16(a0, bf, acc[0][n], 0, 0, 0);
      acc[1][n] = __builtin_amdgcn_mfma_f32_16x16x32_f16(a1, bf, acc[1][n], 0, 0, 0);
    }
  }
  #pragma unroll
  for (int i = 0; i < 2; ++i)
    #pragma unroll
    for (int n = 0; n < 2; ++n)
      #pragma unroll
      for (int r = 0; r < 4; ++r) {
        int o = (w << 5) + (i << 4) + (quad << 2) + r;
        int v = vb + (n << 4) + l16;
        out[o*VS + v] = x[o*VS + v] * (acc[i][n][r] + b1[o]);
      }
}

// ---------------------------------------------------------------------------
// Workspace (floats, total 5,613,824 f = 22.5 MB):
//   [0        , 1769472)  A1 fp32 (dw5 out) -> later D0,D1 fp16
//   [1769472  , 2654208)  A2th [V][128] fp16
//   [2654208  , 4333824)  OFFp [3][81][V] fp16
//   [4333824  , 5218560)  D2 fp16
//   [5218560  , ...)      WTh fp16 | WDh fp16 | W1h fp16
// ---------------------------------------------------------------------------
extern "C" void kernel_launch(void* const* d_in, const int* in_sizes, int n_in,
                              void* d_out, int out_size, void* d_ws, size_t ws_size,
                              hipStream_t stream) {
  (void)in_sizes; (void)n_in; (void)out_size; (void)ws_size;
  const float* x     = (const float*)d_in[0];
  const float* w0    = (const float*)d_in[1];
  const float* b0    = (const float*)d_in[2];
  const float* wsw   = (const float*)d_in[3];
  const float* bs    = (const float*)d_in[4];
  const float* w_off = (const float*)d_in[5];
  const float* b_off = (const float*)d_in[6];
  const float* w_def = (const float*)d_in[7];
  const float* b_def = (const float*)d_in[8];
  const float* w1    = (const float*)d_in[9];
  const float* b1    = (const float*)d_in[10];
  float* out = (float*)d_out;

  float* wsf = (float*)d_ws;
  float*     A1   = wsf;
  _Float16*  A2th = (_Float16*)(wsf + 1769472);
  _Float16*  OFFp = (_Float16*)(wsf + 2654208);
  _Float16*  D2   = (_Float16*)(wsf + 4333824);
  _Float16*  WTh  = (_Float16*)(wsf + 5218560);
  _Float16*  WDh  = WTh + 331776;
  _Float16*  W1h  = WDh + 442368;
  _Float16*  D0   = (_Float16*)A1;          // A1 dead after dwdil
  _Float16*  D1   = D0 + 128*VS;

  prep_weights  <<<225,  256, 0, stream>>>(w_off, w_def, w1, WTh, WDh, W1h);
  dw5_kernel    <<<384,  192, 0, stream>>>(x, w0, b0, A1);
  dwdil_kernel  <<<384,  192, 0, stream>>>(A1, wsw, bs, A2th);
  offconv_kernel<<<1296, 384, 0, stream>>>(A2th, WTh, OFFp);
  deform_kernel <<<1296, 256, 0, stream>>>(A2th, OFFp, b_off, WDh, D0, D1, D2);
  pw_mul_kernel <<<432,  256, 0, stream>>>(D0, D1, D2, b_def, W1h, b1, x, out);
}

// Round 12
// 223.241 us; speedup vs baseline: 1.1585x; 1.1585x over previous
//
#include <hip/hip_runtime.h>

#define CH 128
#define DS 24
#define HW (DS*DS)      // 576
#define VS (DS*DS*DS)   // 13824

typedef _Float16 f16x8 __attribute__((ext_vector_type(8)));
typedef _Float16 half2v __attribute__((ext_vector_type(2)));
typedef __attribute__((ext_vector_type(4))) float f32x4;
typedef _Float16 h4 __attribute__((ext_vector_type(4)));

__device__ __forceinline__ half2v u2h(unsigned u) {
  union { unsigned u; half2v h; } v; v.u = u; return v.h;
}
__device__ __forceinline__ unsigned h2u(half2v h) {
  union { unsigned u; half2v h; } v; v.h = h; return v.u;
}

// sum of 3 fp16 offset partials + bias, row = 3*kn+a
__device__ __forceinline__ float off_sum(const _Float16* __restrict__ OFFp,
                                         const float* __restrict__ b_off,
                                         int kn, int a, int mv) {
  int row = 3*kn + a;
  return (float)OFFp[row*VS + mv] + (float)OFFp[(81 + row)*VS + mv]
       + (float)OFFp[(162 + row)*VS + mv] + b_off[row];
}

// this thread's 2 trilinear corners for tap kn -> Mrow[corner]
__device__ __forceinline__ void meta2(int kn, int mz, int my, int mx,
                                      float po0, float po1, float po2,
                                      int mcp, uint2* Mrow) {
  float cz = (float)(mz + kn/9     - 1) + po0;
  float cy = (float)(my + (kn/3)%3 - 1) + po1;
  float cx = (float)(mx + kn%3     - 1) + po2;
  float fz = floorf(cz), fy = floorf(cy), fx = floorf(cx);
  int iz = (int)fz, iy = (int)fy, ix = (int)fx;
  float rz = cz - fz, ry = cy - fy, rx = cx - fx;
  #pragma unroll
  for (int c2 = 0; c2 < 2; ++c2) {
    int corner = mcp*2 + c2;
    int ca = corner >> 2, cb = (corner >> 1) & 1, cc = corner & 1;
    int zi = iz + ca, yi = iy + cb, xi = ix + cc;
    float ww = (ca ? rz : 1.f-rz) * (cb ? ry : 1.f-ry) * (cc ? rx : 1.f-rx);
    bool valid = ((unsigned)zi < 24u) && ((unsigned)yi < 24u) && ((unsigned)xi < 24u);
    float wv = valid ? ww : 0.f;
    half2v wp = {(_Float16)wv, (_Float16)wv};
    int idx = valid ? (zi*DS + yi)*DS + xi : 0;
    Mrow[corner] = make_uint2(h2u(wp), (unsigned)(idx << 7));
  }
}

// gather one tap's 64x128 B-tile into BlBuf using meta Mb
__device__ __forceinline__ void gather_tap(
    const _Float16* __restrict__ A2th, const uint2 (*Mb)[8],
    _Float16* BlBuf, int cq, int vi0) {
  #pragma unroll
  for (int p = 0; p < 4; ++p) {
    int vl = (p << 4) + vi0;
    half2v a0 = {(_Float16)0.f, (_Float16)0.f};
    half2v a1 = a0, a2 = a0, a3 = a0;
    #pragma unroll
    for (int corner = 0; corner < 8; ++corner) {
      uint2 m = Mb[vl][corner];
      half2v wp = u2h(m.x);
      uint4 g = *(const uint4*)&A2th[m.y + (cq << 3)];
      a0 += u2h(g.x) * wp;
      a1 += u2h(g.y) * wp;
      a2 += u2h(g.z) * wp;
      a3 += u2h(g.w) * wp;
    }
    uint4 pk = {h2u(a0), h2u(a1), h2u(a2), h2u(a3)};
    *(uint4*)&BlBuf[vl*128 + ((cq ^ (vl & 15)) << 3)] = pk;
  }
}

// offconv B chunk: masked shifted-row load / swizzled store
__device__ __forceinline__ uint4 ld_chunk(const _Float16* __restrict__ A2th,
                                          int vb, int s, int k) {
  int vl = s >> 4, cq = s & 15;
  int v = vb + vl;
  int z = v / HW, y = (v / DS) % DS, xx = v % DS;
  int dz = k/9 - 1, dy = (k/3)%3 - 1, dx = k%3 - 1;
  uint4 pk = {0u,0u,0u,0u};
  int zz = z + dz, yy = y + dy, xq = xx + dx;
  if ((unsigned)zz < 24u && (unsigned)yy < 24u && (unsigned)xq < 24u)
    pk = *(const uint4*)&A2th[(v + (dz*DS + dy)*DS + dx)*CH + (cq << 3)];
  return pk;
}
__device__ __forceinline__ void st_chunk(_Float16* Bb, int s, uint4 pk) {
  int vl = s >> 4, cq = s & 15;
  *(uint4*)&Bb[vl*128 + ((cq ^ (vl & 15)) << 3)] = pk;
}

// ---------------------------------------------------------------------------
// K0: weight prep, coalesced via LDS transpose.
// ---------------------------------------------------------------------------
__global__ __launch_bounds__(256) void prep_weights(
    const float* __restrict__ w_off, const float* __restrict__ w_def,
    const float* __restrict__ w1,
    _Float16* __restrict__ WTh, _Float16* __restrict__ WDh,
    _Float16* __restrict__ W1h) {
  __shared__ float sbuf[3456];
  const int b = blockIdx.x, t = threadIdx.x;
  if (b < 96) {
    const int o = b;
    if (o < 81) {
      for (int s = t; s < 3456; s += 256) sbuf[s] = w_off[o*3456 + s];
      __syncthreads();
      for (int s = t; s < 3456; s += 256) {
        int k = s >> 7, c = s & 127;
        WTh[(k*96 + o)*128 + c] = (_Float16)sbuf[c*27 + k];
      }
    } else {
      for (int s = t; s < 3456; s += 256) {
        int k = s >> 7, c = s & 127;
        WTh[(k*96 + o)*128 + c] = (_Float16)0.f;
      }
    }
  } else if (b < 224) {
    const int o = b - 96;
    for (int s = t; s < 3456; s += 256) sbuf[s] = w_def[o*3456 + s];
    __syncthreads();
    for (int s = t; s < 3456; s += 256) {
      int k = s >> 7, c = s & 127;
      WDh[(k*128 + o)*128 + c] = (_Float16)sbuf[c*27 + k];
    }
  } else {
    for (int s = t; s < 16384; s += 256) W1h[s] = (_Float16)w1[s];
  }
}

// ---------------------------------------------------------------------------
// K1: depthwise 5x5x5, pad=2 — LDS-free row-register version.
// ---------------------------------------------------------------------------
__global__ __launch_bounds__(192) void dw5_kernel(
    const float* __restrict__ x, const float* __restrict__ w0,
    const float* __restrict__ b0, float* __restrict__ A1) {
  const int c  = blockIdx.x / 3;
  const int zb = (blockIdx.x % 3) * 8;
  __shared__ float sw[125];
  const int t = threadIdx.x;
  if (t < 125) sw[t] = w0[c*125 + t];
  __syncthreads();
  const int z = zb + t / 24, y = t % 24;
  const float* xc = x + c*VS;
  float acc[24];
  #pragma unroll
  for (int o = 0; o < 24; ++o) acc[o] = 0.f;
  #pragma unroll
  for (int kz = 0; kz < 5; ++kz) {
    int zz = z + kz - 2;
    if ((unsigned)zz >= 24u) continue;
    #pragma unroll
    for (int ky = 0; ky < 5; ++ky) {
      int yy = y + ky - 2;
      if ((unsigned)yy >= 24u) continue;
      const float* row = &xc[(zz*DS + yy)*DS];
      float f[24];
      #pragma unroll
      for (int q = 0; q < 6; ++q) {
        float4 r = *(const float4*)(row + 4*q);
        f[4*q] = r.x; f[4*q+1] = r.y; f[4*q+2] = r.z; f[4*q+3] = r.w;
      }
      const float* wr = &sw[(kz*5 + ky)*5];
      #pragma unroll
      for (int kx = 0; kx < 5; ++kx) {
        float w = wr[kx];
        #pragma unroll
        for (int o = 0; o < 24; ++o) {
          int xi = o + kx - 2;
          if (xi >= 0 && xi < 24) acc[o] = fmaf(w, f[xi], acc[o]);
        }
      }
    }
  }
  const float bias = b0[c];
  float* orow = &A1[c*VS + (z*DS + y)*DS];
  #pragma unroll
  for (int q = 0; q < 6; ++q)
    *(float4*)(orow + 4*q) = make_float4(acc[4*q]+bias, acc[4*q+1]+bias,
                                         acc[4*q+2]+bias, acc[4*q+3]+bias);
}

// ---------------------------------------------------------------------------
// K2: depthwise 5x5x5 dil=3 pad=6 — LDS-free + fused fp16 transpose store.
// ---------------------------------------------------------------------------
__global__ __launch_bounds__(192) void dwdil_kernel(
    const float* __restrict__ A1, const float* __restrict__ wgt,
    const float* __restrict__ bs, _Float16* __restrict__ A2th) {
  const int c  = blockIdx.x / 3;
  const int zb = (blockIdx.x % 3) * 8;
  __shared__ float sw[125];
  const int t = threadIdx.x;
  if (t < 125) sw[t] = wgt[c*125 + t];
  __syncthreads();
  const int z = zb + t / 24, y = t % 24;
  const float* xc = A1 + c*VS;
  float acc[24];
  #pragma unroll
  for (int o = 0; o < 24; ++o) acc[o] = 0.f;
  #pragma unroll
  for (int kz = 0; kz < 5; ++kz) {
    int zz = z + 3*kz - 6;
    if ((unsigned)zz >= 24u) continue;
    #pragma unroll
    for (int ky = 0; ky < 5; ++ky) {
      int yy = y + 3*ky - 6;
      if ((unsigned)yy >= 24u) continue;
      const float* row = &xc[(zz*DS + yy)*DS];
      float f[24];
      #pragma unroll
      for (int q = 0; q < 6; ++q) {
        float4 r = *(const float4*)(row + 4*q);
        f[4*q] = r.x; f[4*q+1] = r.y; f[4*q+2] = r.z; f[4*q+3] = r.w;
      }
      const float* wr = &sw[(kz*5 + ky)*5];
      #pragma unroll
      for (int kx = 0; kx < 5; ++kx) {
        float w = wr[kx];
        #pragma unroll
        for (int o = 0; o < 24; ++o) {
          int xi = o + 3*kx - 6;
          if (xi >= 0 && xi < 24) acc[o] = fmaf(w, f[xi], acc[o]);
        }
      }
    }
  }
  const float bias = bs[c];
  _Float16* dst = &A2th[(z*DS + y)*DS*CH + c];
  #pragma unroll
  for (int o = 0; o < 24; ++o)
    dst[o*CH] = (_Float16)(acc[o] + bias);
}

// ---------------------------------------------------------------------------
// K4: offset conv, f16 MFMA, 64-v tiles, 384 thr / 6 waves (wave = m-tile,
// A-frags direct from global).  Double-buffered Bl, single barrier per tap.
// ---------------------------------------------------------------------------
__global__ __launch_bounds__(384, 5) void offconv_kernel(
    const _Float16* __restrict__ A2th, const _Float16* __restrict__ WTh,
    _Float16* __restrict__ OFFp) {
  const int vb = (blockIdx.x % 216) * 64;
  const int kg = blockIdx.x / 216;          // 0..2
  __shared__ __align__(16) _Float16 Bl[2][64*128];  // 32 KB
  const int t    = threadIdx.x;
  const int lane = t & 63, w = t >> 6;      // w 0..5 = m-tile
  const int l16  = lane & 15, quad = lane >> 4;
  f32x4 acc[4];
  #pragma unroll
  for (int n = 0; n < 4; ++n) acc[n] = (f32x4){0.f,0.f,0.f,0.f};

  const int k0 = kg*9;
  {  // prologue: stage B(k0) -> Bl[0]
    uint4 c0 = ld_chunk(A2th, vb, t,       k0);
    uint4 c1 = ld_chunk(A2th, vb, t + 384, k0);
    uint4 c2 = {0u,0u,0u,0u};
    if (t < 256) c2 = ld_chunk(A2th, vb, t + 768, k0);
    st_chunk(Bl[0], t,       c0);
    st_chunk(Bl[0], t + 384, c1);
    if (t < 256) st_chunk(Bl[0], t + 768, c2);
  }
  __syncthreads();

  for (int i = 0; i < 9; ++i) {
    const int k = k0 + i, bi = i & 1;
    f16x8 af[4];
    #pragma unroll
    for (int ks = 0; ks < 4; ++ks)
      af[ks] = *(const f16x8*)&WTh[(k*96 + (w << 4) + l16)*128 + (ks << 5) + (quad << 3)];
    uint4 c0, c1, c2;
    if (i < 8) {
      c0 = ld_chunk(A2th, vb, t,       k + 1);
      c1 = ld_chunk(A2th, vb, t + 384, k + 1);
      if (t < 256) c2 = ld_chunk(A2th, vb, t + 768, k + 1);
    }
    #pragma unroll
    for (int ks = 0; ks < 4; ++ks) {
      int gx = (((ks << 2) + quad) ^ l16) << 3;
      #pragma unroll
      for (int n = 0; n < 4; ++n) {
        f16x8 bf = *(const f16x8*)&Bl[bi][((n << 4) + l16)*128 + gx];
        acc[n] = __builtin_amdgcn_mfma_f32_16x16x32_f16(af[ks], bf, acc[n], 0, 0, 0);
      }
    }
    if (i < 8) {
      st_chunk(Bl[bi ^ 1], t,       c0);
      st_chunk(Bl[bi ^ 1], t + 384, c1);
      if (t < 256) st_chunk(Bl[bi ^ 1], t + 768, c2);
      __syncthreads();
    }
  }
  #pragma unroll
  for (int n = 0; n < 4; ++n)
    #pragma unroll
    for (int r = 0; r < 4; ++r) {
      int o = (w << 4) + (quad << 2) + r;
      if (o < 81)
        OFFp[(kg*81 + o)*VS + vb + (n << 4) + l16] = (_Float16)acc[n][r];
    }
}

// ---------------------------------------------------------------------------
// K5: deformable conv, f16 MFMA, 64-v tiles, 5 tap-groups (6,6,5,5,5):
// k0 = 0,6,12,17,22, DISJOINT (r11 had tap 17 duplicated).  grid 1080;
// LDS 40KB -> 4 blocks/CU (~16 waves/CU).  Single-barrier pipeline.
// ---------------------------------------------------------------------------
__global__ __launch_bounds__(256, 3) void deform_kernel(
    const _Float16* __restrict__ A2th, const _Float16* __restrict__ OFFp,
    const float* __restrict__ b_off, const _Float16* __restrict__ WDh,
    _Float16* __restrict__ D0, _Float16* __restrict__ D1,
    _Float16* __restrict__ D2, _Float16* __restrict__ D3,
    _Float16* __restrict__ D4) {
  const int vb = (blockIdx.x % 216) * 64;
  const int kg = blockIdx.x / 216;          // 0..4
  _Float16* DP = (kg == 0) ? D0 : (kg == 1) ? D1 : (kg == 2) ? D2
               : (kg == 3) ? D3 : D4;
  const int nt = (kg < 2) ? 6 : 5;                    // sizes 6,6,5,5,5
  const int k0 = (kg < 2) ? kg*6 : 12 + (kg - 2)*5;   // 0,6,12,17,22
  __shared__ __align__(16) _Float16 Bl[2][64*128];  // 32 KB
  __shared__ uint2 M[2][64][8];                     // 8 KB
  const int t    = threadIdx.x;
  const int lane = t & 63, w = t >> 6;
  const int l16  = lane & 15, quad = lane >> 4;
  const int cq = t & 15, vi0 = t >> 4;
  const int mvl = t >> 2, mcp = t & 3;
  const int mv = vb + mvl;
  const int mz = mv / HW, my = (mv / DS) % DS, mx = mv % DS;

  f32x4 acc[2][4];
  #pragma unroll
  for (int i = 0; i < 2; ++i)
    #pragma unroll
    for (int n = 0; n < 4; ++n) acc[i][n] = (f32x4){0.f,0.f,0.f,0.f};

  {
    float p0 = off_sum(OFFp, b_off, k0, 0, mv);
    float p1 = off_sum(OFFp, b_off, k0, 1, mv);
    float p2 = off_sum(OFFp, b_off, k0, 2, mv);
    meta2(k0, mz, my, mx, p0, p1, p2, mcp, &M[0][mvl][0]);
  }
  __syncthreads();
  {
    gather_tap(A2th, M[0], Bl[0], cq, vi0);
    float p0 = off_sum(OFFp, b_off, k0+1, 0, mv);
    float p1 = off_sum(OFFp, b_off, k0+1, 1, mv);
    float p2 = off_sum(OFFp, b_off, k0+1, 2, mv);
    meta2(k0+1, mz, my, mx, p0, p1, p2, mcp, &M[1][mvl][0]);
  }
  __syncthreads();

  for (int i = 0; i < nt; ++i) {
    const int k = k0 + i, bi = i & 1;
    f16x8 af0[4], af1[4];
    #pragma unroll
    for (int ks = 0; ks < 4; ++ks) {
      af0[ks] = *(const f16x8*)&WDh[(k*CH + (w<<5) + l16)*CH + (ks<<5) + (quad<<3)];
      af1[ks] = *(const f16x8*)&WDh[(k*CH + (w<<5) + 16 + l16)*CH + (ks<<5) + (quad<<3)];
    }
    if (i < nt - 1) gather_tap(A2th, M[bi ^ 1], Bl[bi ^ 1], cq, vi0);
    #pragma unroll
    for (int ks = 0; ks < 4; ++ks) {
      int gx = (((ks << 2) + quad) ^ l16) << 3;
      #pragma unroll
      for (int n = 0; n < 4; ++n) {
        f16x8 bf = *(const f16x8*)&Bl[bi][((n << 4) + l16)*128 + gx];
        acc[0][n] = __builtin_amdgcn_mfma_f32_16x16x32_f16(af0[ks], bf, acc[0][n], 0, 0, 0);
        acc[1][n] = __builtin_amdgcn_mfma_f32_16x16x32_f16(af1[ks], bf, acc[1][n], 0, 0, 0);
      }
    }
    if (i < nt - 2) {
      float p0 = off_sum(OFFp, b_off, k+2, 0, mv);
      float p1 = off_sum(OFFp, b_off, k+2, 1, mv);
      float p2 = off_sum(OFFp, b_off, k+2, 2, mv);
      meta2(k+2, mz, my, mx, p0, p1, p2, mcp, &M[bi][mvl][0]);
    }
    if (i < nt - 1) __syncthreads();
  }
  #pragma unroll
  for (int i = 0; i < 2; ++i)
    #pragma unroll
    for (int n = 0; n < 4; ++n)
      #pragma unroll
      for (int r = 0; r < 4; ++r) {
        int o = (w << 5) + (i << 4) + (quad << 2) + r;
        int v = vb + (n << 4) + l16;
        DP[o*VS + v] = (_Float16)acc[i][n][r];
      }
}

// ---------------------------------------------------------------------------
// K6: f16 MFMA 1x1x1 conv + x-multiply, 32-v tiles -> grid 432.
// Bl = D0+..+D4+b_def (fp16 partial sum).
// ---------------------------------------------------------------------------
__global__ __launch_bounds__(256) void pw_mul_kernel(
    const _Float16* __restrict__ D0, const _Float16* __restrict__ D1,
    const _Float16* __restrict__ D2, const _Float16* __restrict__ D3,
    const _Float16* __restrict__ D4, const float* __restrict__ b_def,
    const _Float16* __restrict__ W1h, const float* __restrict__ b1,
    const float* __restrict__ x, float* __restrict__ out) {
  const int vb = blockIdx.x * 32;
  __shared__ __align__(16) _Float16 Wl[128*128]; // 32 KB
  __shared__ __align__(16) _Float16 Bl[32*128];  // 8 KB
  const int t    = threadIdx.x;
  const int lane = t & 63, w = t >> 6;
  const int l16  = lane & 15, quad = lane >> 4;
  const int wo = t >> 4, wcg = t & 15;
  #pragma unroll
  for (int i = 0; i < 8; ++i) {
    int o = wo + 16*i;
    *(uint4*)&Wl[o*128 + ((wcg ^ (o & 15)) << 3)] =
        *(const uint4*)&W1h[o*128 + (wcg << 3)];
  }
  {
    const int vsq = t & 7;     // v = 4*vsq..4*vsq+3
    const int c0  = t >> 3;    // c = c0 + 32*i
    #pragma unroll
    for (int i = 0; i < 4; ++i) {
      int c = c0 + (i << 5);
      float bd = b_def[c];
      int base = c*VS + vb + (vsq << 2);
      h4 a0 = *(const h4*)&D0[base];
      h4 a1 = *(const h4*)&D1[base];
      h4 a2 = *(const h4*)&D2[base];
      h4 a3 = *(const h4*)&D3[base];
      h4 a4 = *(const h4*)&D4[base];
      #pragma unroll
      for (int j = 0; j < 4; ++j) {
        float sum = (float)a0[j] + (float)a1[j] + (float)a2[j]
                  + (float)a3[j] + (float)a4[j] + bd;
        int row = (vsq << 2) + j;
        Bl[row*128 + (((c >> 3) ^ (row & 15)) << 3) + (c & 7)] = (_Float16)sum;
      }
    }
  }
  __syncthreads();
  f32x4 acc[2][2];
  #pragma unroll
  for (int i = 0; i < 2; ++i)
    #pragma unroll
    for (int n = 0; n < 2; ++n) acc[i][n] = (f32x4){0.f,0.f,0.f,0.f};
  #pragma unroll
  for (int ks = 0; ks < 4; ++ks) {
    int gx = (((ks << 2) + quad) ^ l16) << 3;
    f16x8 a0 = *(const f16x8*)&Wl[((w << 5) + l16)*128 + gx];
    f16x8 a1 = *(const f16x8*)&Wl[((w << 5) + 16 + l16)*128 + gx];
    #pragma unroll
    for (int n = 0; n < 2; ++n) {
      f16x8 bf = *(const f16x8*)&Bl[((n << 4) + l16)*128 + gx];
      acc[0][n] = __builtin_amdgcn_mfma_f32_16x16x32_f16(a0, bf, acc[0][n], 0, 0, 0);
      acc[1][n] = __builtin_amdgcn_mfma_f32_16x16x32_f16(a1, bf, acc[1][n], 0, 0, 0);
    }
  }
  #pragma unroll
  for (int i = 0; i < 2; ++i)
    #pragma unroll
    for (int n = 0; n < 2; ++n)
      #pragma unroll
      for (int r = 0; r < 4; ++r) {
        int o = (w << 5) + (i << 4) + (quad << 2) + r;
        int v = vb + (n << 4) + l16;
        out[o*VS + v] = x[o*VS + v] * (acc[i][n][r] + b1[o]);
      }
}

// ---------------------------------------------------------------------------
// Workspace (floats, total 7,383,296 f = 29.5 MB):
//   [0        , 1769472)  A1 fp32 (dw5 out) -> later D0,D1 fp16
//   [1769472  , 2654208)  A2th [V][128] fp16
//   [2654208  , 4333824)  OFFp [3][81][V] fp16
//   [4333824  , 5218560)  D2 fp16
//   [5218560  , 6103296)  D3 fp16
//   [6103296  , 6988032)  D4 fp16
//   [6988032  , 7383296)  WTh fp16 | WDh fp16 | W1h fp16
// ---------------------------------------------------------------------------
extern "C" void kernel_launch(void* const* d_in, const int* in_sizes, int n_in,
                              void* d_out, int out_size, void* d_ws, size_t ws_size,
                              hipStream_t stream) {
  (void)in_sizes; (void)n_in; (void)out_size; (void)ws_size;
  const float* x     = (const float*)d_in[0];
  const float* w0    = (const float*)d_in[1];
  const float* b0    = (const float*)d_in[2];
  const float* wsw   = (const float*)d_in[3];
  const float* bs    = (const float*)d_in[4];
  const float* w_off = (const float*)d_in[5];
  const float* b_off = (const float*)d_in[6];
  const float* w_def = (const float*)d_in[7];
  const float* b_def = (const float*)d_in[8];
  const float* w1    = (const float*)d_in[9];
  const float* b1    = (const float*)d_in[10];
  float* out = (float*)d_out;

  float* wsf = (float*)d_ws;
  float*     A1   = wsf;
  _Float16*  A2th = (_Float16*)(wsf + 1769472);
  _Float16*  OFFp = (_Float16*)(wsf + 2654208);
  _Float16*  D2   = (_Float16*)(wsf + 4333824);
  _Float16*  D3   = (_Float16*)(wsf + 5218560);
  _Float16*  D4   = (_Float16*)(wsf + 6103296);
  _Float16*  WTh  = (_Float16*)(wsf + 6988032);
  _Float16*  WDh  = WTh + 331776;
  _Float16*  W1h  = WDh + 442368;
  _Float16*  D0   = (_Float16*)A1;          // A1 dead after dwdil
  _Float16*  D1   = D0 + 128*VS;

  prep_weights  <<<225,  256, 0, stream>>>(w_off, w_def, w1, WTh, WDh, W1h);
  dw5_kernel    <<<384,  192, 0, stream>>>(x, w0, b0, A1);
  dwdil_kernel  <<<384,  192, 0, stream>>>(A1, wsw, bs, A2th);
  offconv_kernel<<<648,  384, 0, stream>>>(A2th, WTh, OFFp);
  deform_kernel <<<1080, 256, 0, stream>>>(A2th, OFFp, b_off, WDh,
                                           D0, D1, D2, D3, D4);
  pw_mul_kernel <<<432,  256, 0, stream>>>(D0, D1, D2, D3, D4, b_def,
                                           W1h, b1, x, out);
}